// Round 1
// baseline (603.905 us; speedup 1.0000x reference)
//
#include <hip/hip_runtime.h>

// ---------------- types / helpers ----------------
typedef __bf16 bf16;
typedef __attribute__((ext_vector_type(8))) __bf16 bf16x8;
typedef __attribute__((ext_vector_type(4))) float f32x4;

#define AS1U(p) ((const __attribute__((address_space(1))) unsigned int*)(p))
#define AS3U(p) ((__attribute__((address_space(3))) unsigned int*)(p))

__device__ __forceinline__ unsigned short f2bf(float f) {
    union { float f; unsigned int u; } a; a.f = f;
    unsigned int u = a.u;
    u += 0x7fffu + ((u >> 16) & 1u);   // round-to-nearest-even
    return (unsigned short)(u >> 16);
}

// Problem constants
#define MTOT 32768            // B*H*W = 8*64*64
#define DIM  768
#define KP   832              // augmented K: 768 + 16 (mid_q) + 16 (mid_v) + 32 pad
#define NOUT 2304

// ---------------- kernel 0: build B' transposed, bf16 [NOUT][KP] ----------------
// Bt[n][k]: k<768 -> W_qkv[k][n]; 768..783 -> Wb_q[k-768][n] if n<768 else 0;
// 784..799 -> Wb_v[k-784][n-1536] if n>=1536 else 0; k>=800 -> 0.
__global__ __launch_bounds__(256) void bbuild_kernel(
    const float* __restrict__ Wqkv, const float* __restrict__ Wbq,
    const float* __restrict__ Wbv, unsigned short* __restrict__ Bt)
{
    int idx = blockIdx.x * 256 + threadIdx.x;   // 0 .. 2304*832-1, grid sized exactly
    int k = idx % KP;
    int n = idx / KP;
    float v = 0.f;
    if (k < 768) {
        v = Wqkv[(size_t)k * NOUT + n];
    } else if (k < 784) {
        if (n < 768) v = Wbq[(size_t)(k - 768) * 768 + n];
    } else if (k < 800) {
        if (n >= 1536) v = Wbv[(size_t)(k - 784) * 768 + (n - 1536)];
    }
    Bt[idx] = f2bf(v);
}

// ---------------- kernel 1: x -> bf16 A'[:,0:768], zero A'[:,800:832], a_q/a_v ----------------
// Block: 256 threads handles 64 pixels. K-loop over 12 tiles of 64 channels.
__global__ __launch_bounds__(256) void prep_kernel(
    const float* __restrict__ x, const float* __restrict__ Waq,
    const float* __restrict__ Wav, unsigned short* __restrict__ Ap,
    float* __restrict__ aq, float* __restrict__ av)
{
    __shared__ float Xs[64][65];     // +1 pad: conflict-free column reads
    __shared__ float Was[64][32];    // [c][j]  j: 0..15 = Wa_q, 16..31 = Wa_v
    const int t = threadIdx.x;
    const int p0 = blockIdx.x * 64;
    const int pix = t & 63;
    const int j0 = (t >> 6) * 8;     // wave-uniform output-column group
    float acc[8] = {0.f,0.f,0.f,0.f,0.f,0.f,0.f,0.f};

    for (int kt = 0; kt < 12; ++kt) {
        __syncthreads();
        // stage x tile (64 pix x 64 ch) + emit bf16 into A'
        #pragma unroll
        for (int it = 0; it < 4; ++it) {
            int idx = it * 256 + t;           // 0..1023
            int pp = idx >> 4;                // 0..63
            int c4 = (idx & 15) * 4;          // 0..60
            const float4 v = *(const float4*)(x + (size_t)(p0 + pp) * DIM + kt * 64 + c4);
            ushort4 u; u.x = f2bf(v.x); u.y = f2bf(v.y); u.z = f2bf(v.z); u.w = f2bf(v.w);
            *(ushort4*)(Ap + (size_t)(p0 + pp) * KP + kt * 64 + c4) = u;
            Xs[pp][c4 + 0] = v.x; Xs[pp][c4 + 1] = v.y;
            Xs[pp][c4 + 2] = v.z; Xs[pp][c4 + 3] = v.w;
        }
        // stage Wa tile: rows kt*64..+64, 32 cols
        {
            int r = t >> 2;              // 0..63
            int cc = (t & 3) * 8;        // 0,8,16,24
            #pragma unroll
            for (int j = 0; j < 8; ++j) {
                int col = cc + j;
                float wv = (col < 16) ? Waq[(size_t)(kt * 64 + r) * 16 + col]
                                      : Wav[(size_t)(kt * 64 + r) * 16 + (col - 16)];
                Was[r][col] = wv;
            }
        }
        __syncthreads();
        for (int c = 0; c < 64; ++c) {
            float xv = Xs[pix][c];
            float4 w0 = *(const float4*)&Was[c][j0];
            float4 w1 = *(const float4*)&Was[c][j0 + 4];
            acc[0] += xv * w0.x; acc[1] += xv * w0.y; acc[2] += xv * w0.z; acc[3] += xv * w0.w;
            acc[4] += xv * w1.x; acc[5] += xv * w1.y; acc[6] += xv * w1.z; acc[7] += xv * w1.w;
        }
    }
    // write a_q / a_v
    float* dst = (j0 < 16) ? (aq + (size_t)(p0 + pix) * 16 + j0)
                           : (av + (size_t)(p0 + pix) * 16 + (j0 - 16));
    #pragma unroll
    for (int j = 0; j < 8; ++j) dst[j] = acc[j];
    // zero-fill A' pad columns 800..831
    {
        int pp = t >> 2, cc = (t & 3) * 8;
        ushort4 z; z.x = 0; z.y = 0; z.z = 0; z.w = 0;
        *(ushort4*)(Ap + (size_t)(p0 + pp) * KP + 800 + cc) = z;
        *(ushort4*)(Ap + (size_t)(p0 + pp) * KP + 804 + cc) = z;  // cc in {0,8,16,24}: covers 800..831
    }
}

// ---------------- kernel 2: mid = conv3(a)+b3 + conv1(a)+b1 + a, bf16 into A'[:,768+qv*16] ----------------
// 256 blocks: b(8) x tile16(16) x qv(2). Each thread = one pixel of a 16x16 tile, 16 channels.
__global__ __launch_bounds__(256) void conv_mid_kernel(
    const float* __restrict__ aq, const float* __restrict__ av,
    const float* __restrict__ Kq3, const float* __restrict__ bq3,
    const float* __restrict__ Kv3, const float* __restrict__ bv3,
    const float* __restrict__ Kq1, const float* __restrict__ bq1,
    const float* __restrict__ Kv1, const float* __restrict__ bv1,
    unsigned short* __restrict__ Ap)
{
    const int bx = blockIdx.x;
    const int qv   = bx & 1;
    const int tile = (bx >> 1) & 15;
    const int b    = bx >> 5;
    const float* a  = qv ? av  : aq;
    const float* K3 = qv ? Kv3 : Kq3;
    const float* K1 = qv ? Kv1 : Kq1;
    const float* b3 = qv ? bv3 : bq3;
    const float* b1 = qv ? bv1 : bq1;

    __shared__ float K3s[9][16][16];
    __shared__ float K1s[16][16];
    const int t = threadIdx.x;
    for (int i = t; i < 9 * 256; i += 256) ((float*)K3s)[i] = K3[i];
    ((float*)K1s)[t] = K1[t];
    __syncthreads();

    const int lh = t >> 4, lw = t & 15;
    const int h = (tile >> 2) * 16 + lh;
    const int w = (tile & 3) * 16 + lw;

    float acc[16];
    // bias + identity + 1x1 on center
    const float* ac = a + (((size_t)b * 64 + h) * 64 + w) * 16;
    float cen[16];
    #pragma unroll
    for (int i4 = 0; i4 < 4; ++i4) {
        float4 q = ((const float4*)ac)[i4];
        cen[i4 * 4 + 0] = q.x; cen[i4 * 4 + 1] = q.y;
        cen[i4 * 4 + 2] = q.z; cen[i4 * 4 + 3] = q.w;
    }
    #pragma unroll
    for (int o = 0; o < 16; ++o) acc[o] = b3[o] + b1[o] + cen[o];
    #pragma unroll
    for (int i = 0; i < 16; ++i) {
        float vi = cen[i];
        #pragma unroll
        for (int o = 0; o < 16; ++o) acc[o] += vi * K1s[i][o];
    }
    // 3x3 taps
    for (int dh = -1; dh <= 1; ++dh) {
        for (int dw = -1; dw <= 1; ++dw) {
            int hh = h + dh, ww = w + dw;
            if ((unsigned)hh < 64u && (unsigned)ww < 64u) {
                const float* ap = a + (((size_t)b * 64 + hh) * 64 + ww) * 16;
                float v[16];
                #pragma unroll
                for (int i4 = 0; i4 < 4; ++i4) {
                    float4 q = ((const float4*)ap)[i4];
                    v[i4 * 4 + 0] = q.x; v[i4 * 4 + 1] = q.y;
                    v[i4 * 4 + 2] = q.z; v[i4 * 4 + 3] = q.w;
                }
                const int tap = (dh + 1) * 3 + (dw + 1);
                #pragma unroll
                for (int i = 0; i < 16; ++i) {
                    float vi = v[i];
                    #pragma unroll
                    for (int o = 0; o < 16; ++o) acc[o] += vi * K3s[tap][i][o];
                }
            }
        }
    }
    // write bf16 mid into A' columns 768+qv*16 .. +16
    unsigned short* dst = Ap + (((size_t)b * 64 + h) * 64 + w) * KP + 768 + qv * 16;
    #pragma unroll
    for (int o4 = 0; o4 < 4; ++o4) {
        ushort4 u;
        u.x = f2bf(acc[o4 * 4 + 0]); u.y = f2bf(acc[o4 * 4 + 1]);
        u.z = f2bf(acc[o4 * 4 + 2]); u.w = f2bf(acc[o4 * 4 + 3]);
        *(ushort4*)(dst + o4 * 4) = u;
    }
}

// ---------------- kernel 3: GEMM out[M,N] = A'[M,KP] * Bt[N,KP]^T + b_qkv ----------------
// 128x128 tile, BK=64, 4 waves in 2x2, each wave 4x4 of 16x16x32 bf16 MFMA.
// Staging via global_load_lds width-16; XOR chunk-swizzle folded into the GLOBAL
// source address (LDS dest is fixed wave-base + lane*16), so ds_read_b128 frag
// loads spread over 8 bank-groups (2 lanes/group = free per m136).
__global__ __launch_bounds__(256, 2) void gemm_kernel(
    const bf16* __restrict__ A, const bf16* __restrict__ Bt,
    const float* __restrict__ bias, float* __restrict__ out)
{
    __shared__ bf16 As[128 * 64];
    __shared__ bf16 Bs[128 * 64];
    const int t = threadIdx.x;
    const int wave = t >> 6, lane = t & 63;
    const int m0 = blockIdx.y * 128, n0 = blockIdx.x * 128;
    const int wm = wave & 1, wn = wave >> 1;

    f32x4 acc[4][4] = {};

    const int sr = lane >> 3;                 // row within 8-row chunk
    const int ql = (lane & 7) ^ sr;           // logical k-chunk this lane fetches (swizzle)

    for (int kt = 0; kt < 13; ++kt) {
        const int k0 = kt * 64;
        __syncthreads();                      // previous tile's reads complete
        #pragma unroll
        for (int it = 0; it < 4; ++it) {
            int ci = wave * 4 + it;           // 16 chunks of 8 rows
            int r = ci * 8 + sr;
            const bf16* ga = A  + (size_t)(m0 + r) * KP + k0 + ql * 8;
            __builtin_amdgcn_global_load_lds(AS1U(ga), AS3U(As + ci * 512 + lane * 8), 16, 0, 0);
            const bf16* gb = Bt + (size_t)(n0 + r) * KP + k0 + ql * 8;
            __builtin_amdgcn_global_load_lds(AS1U(gb), AS3U(Bs + ci * 512 + lane * 8), 16, 0, 0);
        }
        __syncthreads();                      // compiler drains vmcnt before barrier
        #pragma unroll
        for (int kk = 0; kk < 2; ++kk) {
            bf16x8 af[4], bfr[4];
            const int phys = ((kk << 2) + (lane >> 4)) ^ (lane & 7);  // un-swizzle
            #pragma unroll
            for (int mi = 0; mi < 4; ++mi) {
                int rr = wm * 64 + mi * 16 + (lane & 15);
                af[mi] = *(const bf16x8*)(As + rr * 64 + phys * 8);
            }
            #pragma unroll
            for (int ni = 0; ni < 4; ++ni) {
                int rr = wn * 64 + ni * 16 + (lane & 15);
                bfr[ni] = *(const bf16x8*)(Bs + rr * 64 + phys * 8);
            }
            #pragma unroll
            for (int mi = 0; mi < 4; ++mi)
                #pragma unroll
                for (int ni = 0; ni < 4; ++ni)
                    acc[mi][ni] = __builtin_amdgcn_mfma_f32_16x16x32_bf16(
                        af[mi], bfr[ni], acc[mi][ni], 0, 0, 0);
        }
    }
    // epilogue: C/D layout col=lane&15, row=(lane>>4)*4+reg  [m89/m91]
    #pragma unroll
    for (int ni = 0; ni < 4; ++ni) {
        int col = n0 + wn * 64 + ni * 16 + (lane & 15);
        float bv = bias[col];
        #pragma unroll
        for (int mi = 0; mi < 4; ++mi) {
            int rbase = m0 + wm * 64 + mi * 16 + ((lane >> 4) << 2);
            #pragma unroll
            for (int r = 0; r < 4; ++r)
                out[(size_t)(rbase + r) * NOUT + col] = acc[mi][ni][r] + bv;
        }
    }
}

// ---------------- launch ----------------
extern "C" void kernel_launch(void* const* d_in, const int* in_sizes, int n_in,
                              void* d_out, int out_size, void* d_ws, size_t ws_size,
                              hipStream_t stream) {
    const float* x    = (const float*)d_in[0];
    const float* Wqkv = (const float*)d_in[1];
    const float* bqkv = (const float*)d_in[2];
    const float* Waq  = (const float*)d_in[3];
    const float* Wbq  = (const float*)d_in[4];
    const float* Wav  = (const float*)d_in[5];
    const float* Wbv  = (const float*)d_in[6];
    const float* Kq3  = (const float*)d_in[7];
    const float* bq3  = (const float*)d_in[8];
    const float* Kv3  = (const float*)d_in[9];
    const float* bv3  = (const float*)d_in[10];
    const float* Kq1  = (const float*)d_in[11];
    const float* bq1  = (const float*)d_in[12];
    const float* Kv1  = (const float*)d_in[13];
    const float* bv1  = (const float*)d_in[14];
    float* out = (float*)d_out;

    // workspace layout (total 62,554,112 B)
    char* ws = (char*)d_ws;
    unsigned short* Ap = (unsigned short*)ws;                       // [32768][832] bf16 = 54,525,952 B
    float* aq = (float*)(ws + 54525952);                            // [32768][16]  fp32 =  2,097,152 B
    float* av = (float*)(ws + 54525952 + 2097152);                  // [32768][16]  fp32 =  2,097,152 B
    unsigned short* Bt = (unsigned short*)(ws + 54525952 + 4194304); // [2304][832] bf16 =  3,833,856 B

    bbuild_kernel<<<(NOUT * KP) / 256, 256, 0, stream>>>(Wqkv, Wbq, Wbv, Bt);
    prep_kernel<<<MTOT / 64, 256, 0, stream>>>(x, Waq, Wav, Ap, aq, av);
    conv_mid_kernel<<<256, 256, 0, stream>>>(aq, av, Kq3, bq3, Kv3, bv3,
                                             Kq1, bq1, Kv1, bv1, Ap);
    gemm_kernel<<<dim3(NOUT / 128, MTOT / 128), 256, 0, stream>>>(
        (const bf16*)Ap, (const bf16*)Bt, bqkv, out);
}

// Round 2
// 553.324 us; speedup vs baseline: 1.0914x; 1.0914x over previous
//
#include <hip/hip_runtime.h>

// ---------------- types / helpers ----------------
typedef __bf16 bf16;
typedef __attribute__((ext_vector_type(8))) __bf16 bf16x8;
typedef __attribute__((ext_vector_type(4))) float f32x4;

#define AS1U(p) ((const __attribute__((address_space(1))) unsigned int*)(p))
#define AS3U(p) ((__attribute__((address_space(3))) unsigned int*)(p))

__device__ __forceinline__ unsigned short f2bf(float f) {
    union { float f; unsigned int u; } a; a.f = f;
    unsigned int u = a.u;
    u += 0x7fffu + ((u >> 16) & 1u);   // round-to-nearest-even
    return (unsigned short)(u >> 16);
}
__device__ __forceinline__ unsigned int pk2(float a, float b) {
    return (unsigned int)f2bf(a) | ((unsigned int)f2bf(b) << 16);
}

// Problem constants
#define MTOT 32768            // B*H*W = 8*64*64
#define DIM  768
#define KP   832              // augmented K: 768 + 16 (mid_q) + 16 (mid_v) + 32 pad
#define NOUT 2304

// ---------------- kernel 0: build Bt [NOUT][KP] bf16 + WaT [32][768] bf16 ----------------
// Region A (432 blocks): coalesced 64x64 tile transpose of W_qkv -> Bt[:, 0:768].
// Region B (144 blocks): Bt[:, 768:832] from Wb_q / Wb_v / zeros.
// Region C (96 blocks):  WaT[n][k] = Wa_{q,v}[k][n] (B-operand layout for down-proj MFMA).
__global__ __launch_bounds__(256) void bbuild_kernel(
    const float* __restrict__ Wqkv, const float* __restrict__ Wbq,
    const float* __restrict__ Wbv, const float* __restrict__ Waq,
    const float* __restrict__ Wav, unsigned short* __restrict__ Bt,
    unsigned short* __restrict__ WaT)
{
    const int bx = blockIdx.x;
    const int t = threadIdx.x;
    if (bx < 432) {
        // transpose: kt-tile (12) x nt-tile (36), 64x64 fp32 via LDS
        __shared__ float Ts[64][65];
        const int kt = bx % 12, nt = bx / 12;
        #pragma unroll
        for (int it = 0; it < 4; ++it) {
            int idx = it * 256 + t;          // 0..1023
            int kr = idx >> 4;               // 0..63
            int nc = (idx & 15) * 4;         // 0..60
            float4 v = *(const float4*)(Wqkv + (size_t)(kt * 64 + kr) * NOUT + nt * 64 + nc);
            Ts[kr][nc + 0] = v.x; Ts[kr][nc + 1] = v.y;
            Ts[kr][nc + 2] = v.z; Ts[kr][nc + 3] = v.w;
        }
        __syncthreads();
        #pragma unroll
        for (int it = 0; it < 4; ++it) {
            int idx = it * 256 + t;
            int nr = idx >> 4;               // 0..63
            int kc = (idx & 15) * 4;         // 0..60
            ushort4 u;
            u.x = f2bf(Ts[kc + 0][nr]); u.y = f2bf(Ts[kc + 1][nr]);
            u.z = f2bf(Ts[kc + 2][nr]); u.w = f2bf(Ts[kc + 3][nr]);
            *(ushort4*)(Bt + (size_t)(nt * 64 + nr) * KP + kt * 64 + kc) = u;
        }
    } else if (bx < 576) {
        int idx = (bx - 432) * 256 + t;      // 0..36863
        int n = idx >> 4;                    // 0..2303
        int k = 768 + (idx & 15) * 4;
        ushort4 u;
        unsigned short* up = (unsigned short*)&u;
        #pragma unroll
        for (int j = 0; j < 4; ++j) {
            int kk = k + j;
            float v = 0.f;
            if (kk < 784) { if (n < 768) v = Wbq[(size_t)(kk - 768) * 768 + n]; }
            else if (kk < 800) { if (n >= 1536) v = Wbv[(size_t)(kk - 784) * 768 + (n - 1536)]; }
            up[j] = f2bf(v);
        }
        *(ushort4*)(Bt + (size_t)n * KP + k) = u;
    } else {
        int idx = (bx - 576) * 256 + t;      // 0..24575
        int n = idx / 768, k = idx % 768;
        float v = (n < 16) ? Waq[(size_t)k * 16 + n] : Wav[(size_t)k * 16 + (n - 16)];
        WaT[(size_t)n * 768 + k] = f2bf(v);
    }
}

// ---------------- kernel 1: x -> bf16 A'[:,0:768] + MFMA down-proj a_q/a_v ----------------
// 512 blocks x 64 pixels. Per ktile(64ch): convert x tile to bf16 (global A' +
// swizzled LDS), then 16x16x32 MFMA vs WaT (N=32). fp32 accumulation.
__global__ __launch_bounds__(256) void prep_kernel(
    const float* __restrict__ x, const bf16* __restrict__ WaT,
    unsigned short* __restrict__ Ap, float* __restrict__ aq, float* __restrict__ av)
{
    __shared__ bf16 Xs[64 * 64];
    const int t = threadIdx.x;
    const int wave = t >> 6, lane = t & 63;
    const int l15 = lane & 15, q = lane >> 4;
    const int p0 = blockIdx.x * 64;
    const int row = t >> 2, c16 = (t & 3) * 16;
    const int r8 = row & 7, ch0 = c16 >> 3;
    f32x4 acc[2] = {};

    for (int kt = 0; kt < 12; ++kt) {
        const float* xp = x + (size_t)(p0 + row) * DIM + kt * 64 + c16;
        float4 v0 = *(const float4*)(xp + 0);
        float4 v1 = *(const float4*)(xp + 4);
        float4 v2 = *(const float4*)(xp + 8);
        float4 v3 = *(const float4*)(xp + 12);
        uint4 u0, u1;
        u0.x = pk2(v0.x, v0.y); u0.y = pk2(v0.z, v0.w);
        u0.z = pk2(v1.x, v1.y); u0.w = pk2(v1.z, v1.w);
        u1.x = pk2(v2.x, v2.y); u1.y = pk2(v2.z, v2.w);
        u1.z = pk2(v3.x, v3.y); u1.w = pk2(v3.z, v3.w);
        // global A' (bf16)
        unsigned short* apq = Ap + (size_t)(p0 + row) * KP + kt * 64 + c16;
        *(uint4*)(apq) = u0;
        *(uint4*)(apq + 8) = u1;
        __syncthreads();                       // prev iter's LDS reads done
        // LDS, XOR-swizzled: chunk ch at phys slot ch^(row&7)
        *(uint4*)(Xs + row * 64 + ((ch0 + 0) ^ r8) * 8) = u0;
        *(uint4*)(Xs + row * 64 + ((ch0 + 1) ^ r8) * 8) = u1;
        __syncthreads();
        // B-frags from WaT (wave-shared, L1/L2-hot)
        bf16x8 bfr[2][2];
        #pragma unroll
        for (int kk = 0; kk < 2; ++kk)
            #pragma unroll
            for (int nf = 0; nf < 2; ++nf)
                bfr[kk][nf] = *(const bf16x8*)(WaT + (size_t)(nf * 16 + l15) * 768
                                               + kt * 64 + kk * 32 + q * 8);
        #pragma unroll
        for (int kk = 0; kk < 2; ++kk) {
            int phys = ((kk << 2) + q) ^ (l15 & 7);
            bf16x8 af = *(const bf16x8*)(Xs + (wave * 16 + l15) * 64 + phys * 8);
            acc[0] = __builtin_amdgcn_mfma_f32_16x16x32_bf16(af, bfr[kk][0], acc[0], 0, 0, 0);
            acc[1] = __builtin_amdgcn_mfma_f32_16x16x32_bf16(af, bfr[kk][1], acc[1], 0, 0, 0);
        }
    }
    // write a_q / a_v: C/D layout col=lane&15, row=q*4+r
    const int m = wave * 16 + q * 4;
    #pragma unroll
    for (int r = 0; r < 4; ++r) {
        aq[(size_t)(p0 + m + r) * 16 + l15] = acc[0][r];
        av[(size_t)(p0 + m + r) * 16 + l15] = acc[1][r];
    }
    // zero-fill A' pad columns 800..831
    uint4 z; z.x = z.y = z.z = z.w = 0u;
    *(uint4*)(Ap + (size_t)(p0 + row) * KP + 800 + (t & 3) * 8) = z;
}

// ---------------- kernel 2: mid = conv3(a)+b3 + conv1(a)+b1 + a -> A'[:,768+qv*16] ----------------
__global__ __launch_bounds__(256) void conv_mid_kernel(
    const float* __restrict__ aq, const float* __restrict__ av,
    const float* __restrict__ Kq3, const float* __restrict__ bq3,
    const float* __restrict__ Kv3, const float* __restrict__ bv3,
    const float* __restrict__ Kq1, const float* __restrict__ bq1,
    const float* __restrict__ Kv1, const float* __restrict__ bv1,
    unsigned short* __restrict__ Ap)
{
    const int bx = blockIdx.x;
    const int qv   = bx & 1;
    const int tile = (bx >> 1) & 15;
    const int b    = bx >> 5;
    const float* a  = qv ? av  : aq;
    const float* K3 = qv ? Kv3 : Kq3;
    const float* K1 = qv ? Kv1 : Kq1;
    const float* b3 = qv ? bv3 : bq3;
    const float* b1 = qv ? bv1 : bq1;

    __shared__ float K3s[9][16][16];
    __shared__ float K1s[16][16];
    const int t = threadIdx.x;
    for (int i = t; i < 9 * 256; i += 256) ((float*)K3s)[i] = K3[i];
    ((float*)K1s)[t] = K1[t];
    __syncthreads();

    const int lh = t >> 4, lw = t & 15;
    const int h = (tile >> 2) * 16 + lh;
    const int w = (tile & 3) * 16 + lw;

    float acc[16];
    const float* ac = a + (((size_t)b * 64 + h) * 64 + w) * 16;
    float cen[16];
    #pragma unroll
    for (int i4 = 0; i4 < 4; ++i4) {
        float4 qd = ((const float4*)ac)[i4];
        cen[i4 * 4 + 0] = qd.x; cen[i4 * 4 + 1] = qd.y;
        cen[i4 * 4 + 2] = qd.z; cen[i4 * 4 + 3] = qd.w;
    }
    #pragma unroll
    for (int o = 0; o < 16; ++o) acc[o] = b3[o] + b1[o] + cen[o];
    #pragma unroll
    for (int i = 0; i < 16; ++i) {
        float vi = cen[i];
        #pragma unroll
        for (int o = 0; o < 16; ++o) acc[o] += vi * K1s[i][o];
    }
    for (int dh = -1; dh <= 1; ++dh) {
        for (int dw = -1; dw <= 1; ++dw) {
            int hh = h + dh, ww = w + dw;
            if ((unsigned)hh < 64u && (unsigned)ww < 64u) {
                const float* ap = a + (((size_t)b * 64 + hh) * 64 + ww) * 16;
                float v[16];
                #pragma unroll
                for (int i4 = 0; i4 < 4; ++i4) {
                    float4 qd = ((const float4*)ap)[i4];
                    v[i4 * 4 + 0] = qd.x; v[i4 * 4 + 1] = qd.y;
                    v[i4 * 4 + 2] = qd.z; v[i4 * 4 + 3] = qd.w;
                }
                const int tap = (dh + 1) * 3 + (dw + 1);
                #pragma unroll
                for (int i = 0; i < 16; ++i) {
                    float vi = v[i];
                    #pragma unroll
                    for (int o = 0; o < 16; ++o) acc[o] += vi * K3s[tap][i][o];
                }
            }
        }
    }
    unsigned short* dst = Ap + (((size_t)b * 64 + h) * 64 + w) * KP + 768 + qv * 16;
    #pragma unroll
    for (int o4 = 0; o4 < 4; ++o4) {
        ushort4 u;
        u.x = f2bf(acc[o4 * 4 + 0]); u.y = f2bf(acc[o4 * 4 + 1]);
        u.z = f2bf(acc[o4 * 4 + 2]); u.w = f2bf(acc[o4 * 4 + 3]);
        *(ushort4*)(dst + o4 * 4) = u;
    }
}

// ---------------- kernel 3: GEMM out[M,N] = A'[M,KP] * Bt[N,KP]^T + b_qkv ----------------
// 128x128 tile, BK=64, 4 waves 2x2, each 4x4 of 16x16x32 bf16 MFMA.
// global_load_lds width-16 with XOR chunk-swizzle folded into the global address.
__global__ __launch_bounds__(256, 2) void gemm_kernel(
    const bf16* __restrict__ A, const bf16* __restrict__ Bt,
    const float* __restrict__ bias, float* __restrict__ out)
{
    __shared__ bf16 As[128 * 64];
    __shared__ bf16 Bs[128 * 64];
    const int t = threadIdx.x;
    const int wave = t >> 6, lane = t & 63;
    const int m0 = blockIdx.y * 128, n0 = blockIdx.x * 128;
    const int wm = wave & 1, wn = wave >> 1;

    f32x4 acc[4][4] = {};

    const int sr = lane >> 3;                 // row within 8-row chunk
    const int ql = (lane & 7) ^ sr;           // logical k-chunk this lane fetches (swizzle)

    for (int kt = 0; kt < 13; ++kt) {
        const int k0 = kt * 64;
        __syncthreads();
        #pragma unroll
        for (int it = 0; it < 4; ++it) {
            int ci = wave * 4 + it;           // 16 chunks of 8 rows
            int r = ci * 8 + sr;
            const bf16* ga = A  + (size_t)(m0 + r) * KP + k0 + ql * 8;
            __builtin_amdgcn_global_load_lds(AS1U(ga), AS3U(As + ci * 512 + lane * 8), 16, 0, 0);
            const bf16* gb = Bt + (size_t)(n0 + r) * KP + k0 + ql * 8;
            __builtin_amdgcn_global_load_lds(AS1U(gb), AS3U(Bs + ci * 512 + lane * 8), 16, 0, 0);
        }
        __syncthreads();
        #pragma unroll
        for (int kk = 0; kk < 2; ++kk) {
            bf16x8 af[4], bfr[4];
            const int phys = ((kk << 2) + (lane >> 4)) ^ (lane & 7);  // un-swizzle
            #pragma unroll
            for (int mi = 0; mi < 4; ++mi) {
                int rr = wm * 64 + mi * 16 + (lane & 15);
                af[mi] = *(const bf16x8*)(As + rr * 64 + phys * 8);
            }
            #pragma unroll
            for (int ni = 0; ni < 4; ++ni) {
                int rr = wn * 64 + ni * 16 + (lane & 15);
                bfr[ni] = *(const bf16x8*)(Bs + rr * 64 + phys * 8);
            }
            #pragma unroll
            for (int mi = 0; mi < 4; ++mi)
                #pragma unroll
                for (int ni = 0; ni < 4; ++ni)
                    acc[mi][ni] = __builtin_amdgcn_mfma_f32_16x16x32_bf16(
                        af[mi], bfr[ni], acc[mi][ni], 0, 0, 0);
        }
    }
    // epilogue: C/D layout col=lane&15, row=(lane>>4)*4+reg
    #pragma unroll
    for (int ni = 0; ni < 4; ++ni) {
        int col = n0 + wn * 64 + ni * 16 + (lane & 15);
        float bv = bias[col];
        #pragma unroll
        for (int mi = 0; mi < 4; ++mi) {
            int rbase = m0 + wm * 64 + mi * 16 + ((lane >> 4) << 2);
            #pragma unroll
            for (int r = 0; r < 4; ++r)
                out[(size_t)(rbase + r) * NOUT + col] = acc[mi][ni][r] + bv;
        }
    }
}

// ---------------- launch ----------------
extern "C" void kernel_launch(void* const* d_in, const int* in_sizes, int n_in,
                              void* d_out, int out_size, void* d_ws, size_t ws_size,
                              hipStream_t stream) {
    const float* x    = (const float*)d_in[0];
    const float* Wqkv = (const float*)d_in[1];
    const float* bqkv = (const float*)d_in[2];
    const float* Waq  = (const float*)d_in[3];
    const float* Wbq  = (const float*)d_in[4];
    const float* Wav  = (const float*)d_in[5];
    const float* Wbv  = (const float*)d_in[6];
    const float* Kq3  = (const float*)d_in[7];
    const float* bq3  = (const float*)d_in[8];
    const float* Kv3  = (const float*)d_in[9];
    const float* bv3  = (const float*)d_in[10];
    const float* Kq1  = (const float*)d_in[11];
    const float* bq1  = (const float*)d_in[12];
    const float* Kv1  = (const float*)d_in[13];
    const float* bv1  = (const float*)d_in[14];
    float* out = (float*)d_out;

    // workspace layout (total 62,603,264 B)
    char* ws = (char*)d_ws;
    unsigned short* Ap  = (unsigned short*)ws;                        // [32768][832] bf16
    float* aq           = (float*)(ws + 54525952);                    // [32768][16] fp32
    float* av           = (float*)(ws + 54525952 + 2097152);          // [32768][16] fp32
    unsigned short* Bt  = (unsigned short*)(ws + 54525952 + 4194304); // [2304][832] bf16
    unsigned short* WaT = (unsigned short*)(ws + 62554112);           // [32][768] bf16

    bbuild_kernel<<<672, 256, 0, stream>>>(Wqkv, Wbq, Wbv, Waq, Wav, Bt, WaT);
    prep_kernel<<<MTOT / 64, 256, 0, stream>>>(x, (const bf16*)WaT, Ap, aq, av);
    conv_mid_kernel<<<256, 256, 0, stream>>>(aq, av, Kq3, bq3, Kv3, bv3,
                                             Kq1, bq1, Kv1, bv1, Ap);
    gemm_kernel<<<dim3(NOUT / 128, MTOT / 128), 256, 0, stream>>>(
        (const bf16*)Ap, (const bf16*)Bt, bqkv, out);
}